// Round 10
// baseline (721.757 us; speedup 1.0000x reference)
//
#include <hip/hip_runtime.h>
#include <hip/hip_bf16.h>

// GCN (bf16): hs1 = dinv*(xb@W1); z1 = prelu(dv*(sum hs1)+b1); hs2 = dinv*(z1@W2);
// z2 = prelu(dv*(sum hs2)+b2); z = BN(z2) [f32]; p = prelu(BN2(z2 @ (sc*W) + sh@W))
// [BN1-apply folded into proj weights; proj_b cancels in BN2]; out = [z | p] (f32)
//
// R10: segcnt padded 1 counter/64B line (R5 lesson: atomics-with-return serialize
// per LINE: 153K res. on 25 lines ~ 110us hidden in k_binh); CHUNK 2048 / NPB 64
// for 782-block occupancy; BN1 folded into proj GEMM (drops zb write).

#define CAP 96          // max in-degree capacity (actual max deg ~60); multiple of 16
#define NPB 64          // nodes per bucket
#define CHUNK 2048      // edges per k_binh block
#define SEGBIG 2432     // entries per bucket segment (mean 2046 + 8 sigma)
#define MAXBKT 1024     // supports N up to 65536
#define SEGSTR 16       // segcnt stride (ints) = one counter per 64B line

typedef __attribute__((ext_vector_type(8))) short short8;
typedef __attribute__((ext_vector_type(4))) float f32x4;

__device__ __forceinline__ float bf2f(unsigned short u) {
    union { unsigned int i; float f; } v; v.i = ((unsigned int)u) << 16; return v.f;
}
__device__ __forceinline__ unsigned short f2bf(float f) {
    __hip_bfloat16 h = __float2bfloat16(f);   // RNE
    return *reinterpret_cast<unsigned short*>(&h);
}

// ---------------- zero: segcnt (line-strided), stats ----------------
__global__ __launch_bounds__(256) void k_zero(int* segcnt, int nbkt, float* stats) {
    int i = blockIdx.x * 256 + threadIdx.x;
    if (i < nbkt * SEGSTR) segcnt[i] = 0;
    if (i < 2048) stats[i] = 0.0f;
}

// zero sentinel row N of the gather-source buffer
__global__ __launch_bounds__(64) void k_zrow(unsigned short* hs, int N) {
    ((ushort4*)hs)[(size_t)N * 64 + threadIdx.x] = ushort4{0, 0, 0, 0};
}

// ---------------- phase 1: LDS-histogram binning by destination bucket ----------------
__global__ __launch_bounds__(256) void k_binh(const int* __restrict__ row, const int* __restrict__ col,
                                              unsigned* __restrict__ bins, int* __restrict__ segcnt,
                                              int E, int nbkt) {
    __shared__ int hist[MAXBKT];
    __shared__ int base[MAXBKT];
    int e0 = blockIdx.x * CHUNK;
    int eend = e0 + CHUNK; if (eend > E) eend = E;
    for (int b = threadIdx.x; b < nbkt; b += 256) hist[b] = 0;
    __syncthreads();
    for (int e = e0 + threadIdx.x; e < eend; e += 256)
        atomicAdd(&hist[col[e] >> 6], 1);
    __syncthreads();
    for (int b = threadIdx.x; b < nbkt; b += 256) {
        int h = hist[b];
        base[b] = h ? atomicAdd(&segcnt[b * SEGSTR], h) : 0;   // line-padded counter
        hist[b] = 0;                       // reuse as running offset
    }
    __syncthreads();
    for (int e = e0 + threadIdx.x; e < eend; e += 256) {
        int v = col[e], r = row[e];
        int b = v >> 6;
        int p = base[b] + atomicAdd(&hist[b], 1);
        if (p < SEGBIG) bins[(size_t)b * SEGBIG + p] = ((unsigned)r << 6) | (unsigned)(v & (NPB - 1));
    }
}

// ---------------- phase 2: per-bucket CSR scatter + dinv + pad-to-16 ----------------
__global__ __launch_bounds__(256) void k_csr(const unsigned* __restrict__ bins, const int* __restrict__ segcnt,
                                             int* __restrict__ csr, int* __restrict__ fillp,
                                             float* __restrict__ dinv, int N) {
    __shared__ int cnt[NPB];
    int bkt = blockIdx.x;
    if (threadIdx.x < NPB) cnt[threadIdx.x] = 0;
    __syncthreads();
    int m = segcnt[bkt * SEGSTR]; if (m > SEGBIG) m = SEGBIG;
    const unsigned* b = bins + (size_t)bkt * SEGBIG;
    for (int i = threadIdx.x; i < m; i += 256) {
        unsigned ent = b[i];
        int loc = (int)(ent & (NPB - 1));
        int r   = (int)(ent >> 6);
        int p = atomicAdd(&cnt[loc], 1);
        if (p < CAP) csr[(size_t)(bkt * NPB + loc) * CAP + p] = r;
    }
    __syncthreads();
    if (threadIdx.x < NPB) {
        int v = bkt * NPB + threadIdx.x;
        if (v < N) {
            int c = cnt[threadIdx.x];
            int real = c < CAP ? c : CAP;
            int pc = (real + 15) & ~15;           // pad to multiple of 16
            if (pc > CAP) pc = CAP;
            int* lst = csr + (size_t)v * CAP;
            for (int p = real; p < pc; ++p) lst[p] = N;   // sentinel: hs row N = 0
            fillp[v] = pc;
            dinv[v] = rsqrtf(1.0f + (float)c);    // +1 self loop
        }
    }
}

// ---------------- cast f32 -> bf16 (vectorized) ----------------
__global__ __launch_bounds__(256) void k_castx(const float* __restrict__ x, unsigned short* __restrict__ xb, size_t n4) {
    size_t stride = (size_t)gridDim.x * blockDim.x;
    for (size_t i = (size_t)blockIdx.x * blockDim.x + threadIdx.x; i < n4; i += stride) {
        float4 v = ((const float4*)x)[i];
        ushort4 o; o.x = f2bf(v.x); o.y = f2bf(v.y); o.z = f2bf(v.z); o.w = f2bf(v.w);
        ((ushort4*)xb)[i] = o;
    }
}

// ---------------- W [256,256] f32 -> Wt [n][k] bf16 (transpose+cast, opt. col-scale) --------
// scp: if non-null, Wt[n][k] = scp[k]*W[k][n]  (BN1 scale folded into proj weights)
__global__ __launch_bounds__(256) void k_wt(const float* __restrict__ W, unsigned short* __restrict__ Wt,
                                            const float* __restrict__ scp) {
    __shared__ float t[32][33];
    int bx = blockIdx.x * 32, by = blockIdx.y * 32;
    int x = threadIdx.x & 31, y = threadIdx.x >> 5;   // 32x8
#pragma unroll
    for (int i = 0; i < 32; i += 8) {
        float s = scp ? scp[by + y + i] : 1.0f;
        t[y + i][x] = W[(size_t)(by + y + i) * 256 + bx + x] * s;
    }
    __syncthreads();
#pragma unroll
    for (int i = 0; i < 32; i += 8)
        Wt[(size_t)(bx + y + i) * 256 + by + x] = f2bf(t[x][y + i]);  // Wt[n][k] = sc[k]*W[k][n]
}

// ---------------- t[n] = sum_k sh[k]*W[k][n]  (BN1 shift through proj) ----------------
__global__ __launch_bounds__(256) void k_tvec(const float* __restrict__ W, const float* __restrict__ sh,
                                              float* __restrict__ tvec) {
    int n = threadIdx.x;
    float s = 0.0f;
    for (int k = 0; k < 256; ++k) s += sh[k] * W[(size_t)k * 256 + n];
    tvec[n] = s;
}

// ---------------- bf16 MFMA GEMM + LDS-staged coalesced epilogue ----------------
// C[M,256] = A[M,256] @ B (Bt[n][k]); use_scale: *dinv[row]; use_bias: + tvec[col].
__global__ __launch_bounds__(256) void k_gemm_bf16(const unsigned short* __restrict__ A,
                                                   const unsigned short* __restrict__ Bt,
                                                   unsigned short* __restrict__ C,
                                                   const float* __restrict__ dinv, int use_scale,
                                                   const float* __restrict__ tvec, int use_bias,
                                                   int M) {
    __shared__ unsigned short buf[16384];     // As|Bs during K-loop; C-stage reuses all 32KB
    unsigned short* As = buf;
    unsigned short* Bs = buf + 8192;
    int tid  = threadIdx.x;
    int lane = tid & 63, wid = tid >> 6;
    int wr = wid >> 1, wc = wid & 1;
    int row0 = blockIdx.x * 128;
    int col0 = blockIdx.y * 128;

    f32x4 acc[4][4];
#pragma unroll
    for (int m = 0; m < 4; ++m)
#pragma unroll
        for (int n = 0; n < 4; ++n) acc[m][n] = f32x4{0.f, 0.f, 0.f, 0.f};

    int srow = lane >> 3;          // 0..7
    int sk   = (lane & 7) * 8;     // 0,8,...,56

    for (int k0 = 0; k0 < 256; k0 += 64) {
#pragma unroll
        for (int i = 0; i < 4; ++i) {
            int u = i * 4 + wid;                       // load unit 0..15, wave-uniform
            int arow = row0 + u * 8 + srow;
            if (arow >= M) arow = M - 1;               // per-lane source clamp (dest stays linear)
            const unsigned short* ga = A  + (size_t)arow * 256 + k0 + sk;
            const unsigned short* gb = Bt + (size_t)(col0 + u * 8 + srow) * 256 + k0 + sk;
            __builtin_amdgcn_global_load_lds((const __attribute__((address_space(1))) void*)ga,
                (__attribute__((address_space(3))) void*)(As + u * 512), 16, 0, 0);
            __builtin_amdgcn_global_load_lds((const __attribute__((address_space(1))) void*)gb,
                (__attribute__((address_space(3))) void*)(Bs + u * 512), 16, 0, 0);
        }
        __syncthreads();
#pragma unroll
        for (int kk = 0; kk < 64; kk += 32) {
            short8 a[4], b[4];
#pragma unroll
            for (int m = 0; m < 4; ++m)
                a[m] = *(const short8*)(As + (wr * 64 + m * 16 + (lane & 15)) * 64 + kk + (lane >> 4) * 8);
#pragma unroll
            for (int n = 0; n < 4; ++n)
                b[n] = *(const short8*)(Bs + (wc * 64 + n * 16 + (lane & 15)) * 64 + kk + (lane >> 4) * 8);
#pragma unroll
            for (int m = 0; m < 4; ++m)
#pragma unroll
                for (int n = 0; n < 4; ++n)
                    acc[m][n] = __builtin_amdgcn_mfma_f32_16x16x32_bf16(a[m], b[n], acc[m][n], 0, 0, 0);
        }
        __syncthreads();
    }

    // bias (f32, per-column) applied before bf16 staging
    float tn[4] = {0.f, 0.f, 0.f, 0.f};
    if (use_bias) {
#pragma unroll
        for (int n = 0; n < 4; ++n) tn[n] = tvec[col0 + wc * 64 + n * 16 + (lane & 15)];
    }
    // stage C tile (bf16) into LDS; MFMA C/D layout: col=lane&15, row=(lane>>4)*4+r
#pragma unroll
    for (int m = 0; m < 4; ++m)
#pragma unroll
        for (int r = 0; r < 4; ++r) {
            int lr = wr * 64 + m * 16 + (lane >> 4) * 4 + r;
#pragma unroll
            for (int n = 0; n < 4; ++n)
                buf[lr * 128 + wc * 64 + n * 16 + (lane & 15)] = f2bf(acc[m][n][r] + tn[n]);
        }
    __syncthreads();
    // coalesced store: 2048 chunks of 16B; optional per-row dinv prescale
#pragma unroll
    for (int j = 0; j < 8; ++j) {
        int c = j * 256 + tid;
        int r = c >> 4, cc = c & 15;
        int grow = row0 + r;
        if (grow < M) {
            short8 v = *(const short8*)(buf + r * 128 + cc * 8);
            if (use_scale) {
                float d = dinv[grow];
                short8 o;
#pragma unroll
                for (int t = 0; t < 8; ++t)
                    o[t] = (short)f2bf(bf2f((unsigned short)v[t]) * d);
                v = o;
            }
            *(short8*)(C + (size_t)grow * 256 + col0 + cc * 8) = v;
        }
    }
}

// ---------------- aggregation: pure 16-wide row sum (hs prescaled) ----------------
__global__ __launch_bounds__(256) void k_agg_bf(const unsigned short* __restrict__ hs,
                                                unsigned short* __restrict__ outb,
                                                const float* __restrict__ dinv, const int* __restrict__ csr,
                                                const int* __restrict__ fillp, const float* __restrict__ bias,
                                                const float* __restrict__ aptr, int N) {
    int wv = threadIdx.x >> 6, lane = threadIdx.x & 63;   // one node per wave, 4 ch/lane
    int v = blockIdx.x * 4 + wv;
    if (v >= N) return;
    const ushort4* h4 = (const ushort4*)hs;
    float dv = dinv[v];
    ushort4 hv = h4[(size_t)v * 64 + lane];
    float s0 = bf2f(hv.x), s1 = bf2f(hv.y), s2 = bf2f(hv.z), s3 = bf2f(hv.w);
    int n = fillp[v];                      // multiple of 16 (sentinel-padded)
    const int* lst = csr + (size_t)v * CAP;
    for (int i = 0; i < n; i += 16) {
        int u[16];
        ushort4 a[16];
#pragma unroll
        for (int t = 0; t < 16; ++t) u[t] = lst[i + t];
#pragma unroll
        for (int t = 0; t < 16; ++t) a[t] = h4[(size_t)u[t] * 64 + lane];
#pragma unroll
        for (int t = 0; t < 16; ++t) {
            s0 += bf2f(a[t].x); s1 += bf2f(a[t].y);
            s2 += bf2f(a[t].z); s3 += bf2f(a[t].w);
        }
    }
    float al = *aptr;
    float4 bb = *(const float4*)(bias + lane * 4);
    float o0 = dv * s0 + bb.x, o1 = dv * s1 + bb.y, o2 = dv * s2 + bb.z, o3 = dv * s3 + bb.w;
    o0 = o0 >= 0.f ? o0 : al * o0;
    o1 = o1 >= 0.f ? o1 : al * o1;
    o2 = o2 >= 0.f ? o2 : al * o2;
    o3 = o3 >= 0.f ? o3 : al * o3;
    ushort4 o; o.x = f2bf(o0); o.y = f2bf(o1); o.z = f2bf(o2); o.w = f2bf(o3);
    ((ushort4*)outb)[(size_t)v * 64 + lane] = o;
}

// ---------------- BN column stats (vectorized ushort4) ----------------
__global__ __launch_bounds__(256) void k_bnstats_v(const unsigned short* __restrict__ X, float* __restrict__ sums, int N) {
    int w = threadIdx.x >> 6, lane = threadIdx.x & 63;
    int c4 = lane * 4;
    float4 s = {0.f, 0.f, 0.f, 0.f}, q = {0.f, 0.f, 0.f, 0.f};
    int rstride = gridDim.x * 4;
    for (int r = blockIdx.x * 4 + w; r < N; r += rstride) {
        ushort4 x4 = ((const ushort4*)X)[(size_t)r * 64 + lane];
        float a = bf2f(x4.x), b = bf2f(x4.y), c = bf2f(x4.z), d = bf2f(x4.w);
        s.x += a; s.y += b; s.z += c; s.w += d;
        q.x += a * a; q.y += b * b; q.z += c * c; q.w += d * d;
    }
    atomicAdd(&sums[c4 + 0], s.x); atomicAdd(&sums[c4 + 1], s.y);
    atomicAdd(&sums[c4 + 2], s.z); atomicAdd(&sums[c4 + 3], s.w);
    atomicAdd(&sums[256 + c4 + 0], q.x); atomicAdd(&sums[256 + c4 + 1], q.y);
    atomicAdd(&sums[256 + c4 + 2], q.z); atomicAdd(&sums[256 + c4 + 3], q.w);
}

__global__ __launch_bounds__(256) void k_bnfinal(float* stats, const float* __restrict__ gamma,
                                                 const float* __restrict__ beta, float invN) {
    int c = threadIdx.x;
    float mu = stats[c] * invN;
    float var = stats[256 + c] * invN - mu * mu;
    float rstd = rsqrtf(var + 1e-5f);
    float sc = rstd * gamma[c];
    stats[512 + c] = sc;
    stats[768 + c] = beta[c] - mu * sc;
}

// ---------------- BN apply for z: f32 out only ----------------
__global__ __launch_bounds__(256) void k_bnapply_z(const unsigned short* __restrict__ in,
                                                   float* __restrict__ zout,
                                                   const float* __restrict__ scale, const float* __restrict__ shift,
                                                   size_t n4) {
    size_t stride = (size_t)gridDim.x * blockDim.x;
    for (size_t i = (size_t)blockIdx.x * blockDim.x + threadIdx.x; i < n4; i += stride) {
        int c4 = (int)(i & 63) * 4;
        ushort4 x4 = ((const ushort4*)in)[i];
        float4 sc = *(const float4*)(scale + c4);
        float4 sh = *(const float4*)(shift + c4);
        float4 y;
        y.x = bf2f(x4.x) * sc.x + sh.x;
        y.y = bf2f(x4.y) * sc.y + sh.y;
        y.z = bf2f(x4.z) * sc.z + sh.z;
        y.w = bf2f(x4.w) * sc.w + sh.w;
        ((float4*)zout)[i] = y;
    }
}

// ---------------- BN apply for p: prelu, f32 out ----------------
__global__ __launch_bounds__(256) void k_bnapply_p(const unsigned short* __restrict__ in,
                                                   float* __restrict__ pout,
                                                   const float* __restrict__ scale, const float* __restrict__ shift,
                                                   const float* __restrict__ aptr, size_t n4) {
    size_t stride = (size_t)gridDim.x * blockDim.x;
    float a = *aptr;
    for (size_t i = (size_t)blockIdx.x * blockDim.x + threadIdx.x; i < n4; i += stride) {
        int c4 = (int)(i & 63) * 4;
        ushort4 x4 = ((const ushort4*)in)[i];
        float4 sc = *(const float4*)(scale + c4);
        float4 sh = *(const float4*)(shift + c4);
        float4 y;
        y.x = bf2f(x4.x) * sc.x + sh.x;
        y.y = bf2f(x4.y) * sc.y + sh.y;
        y.z = bf2f(x4.z) * sc.z + sh.z;
        y.w = bf2f(x4.w) * sc.w + sh.w;
        y.x = y.x >= 0.f ? y.x : a * y.x;
        y.y = y.y >= 0.f ? y.y : a * y.y;
        y.z = y.z >= 0.f ? y.z : a * y.z;
        y.w = y.w >= 0.f ? y.w : a * y.w;
        ((float4*)pout)[i] = y;
    }
}

extern "C" void kernel_launch(void* const* d_in, const int* in_sizes, int n_in,
                              void* d_out, int out_size, void* d_ws, size_t ws_size,
                              hipStream_t stream) {
    const float* x     = (const float*)d_in[0];
    const int*   ei    = (const int*)d_in[1];
    const float* W1    = (const float*)d_in[2];
    const float* b1    = (const float*)d_in[3];
    const float* W2    = (const float*)d_in[4];
    const float* b2    = (const float*)d_in[5];
    const float* aptr  = (const float*)d_in[6];
    const float* gamma = (const float*)d_in[7];
    const float* beta  = (const float*)d_in[8];
    const float* projW = (const float*)d_in[9];
    // d_in[10] = proj_b: cancels inside BN2, unused
    const float* pgamma = (const float*)d_in[11];
    const float* pbeta  = (const float*)d_in[12];
    const float* a2ptr  = (const float*)d_in[13];

    int N = in_sizes[0] / 256;
    int E = in_sizes[1] / 2;
    const int* row = ei;
    const int* col = ei + E;

    float* out  = (float*)d_out;
    float* zout = out;
    float* pout = out + (size_t)N * 256;

    int nbkt = (N + NPB - 1) / NPB;

    // workspace: B0|B1|B2 bf16 [(N+1),256], Wt x3, dinv, fillp, csr, stats(+tvec), segcnt, bins
    size_t rowsz = (size_t)(N + 1) * 256;
    unsigned short* B0 = (unsigned short*)d_ws;
    unsigned short* B1 = B0 + rowsz;
    unsigned short* B2 = B1 + rowsz;
    unsigned short* Wt = B2 + rowsz;
    float* dinv  = (float*)(Wt + 3 * 65536);
    int*   fillp = (int*)(dinv + N + 1);
    int*   csr   = fillp + N;
    float* stats = (float*)(csr + (size_t)N * CAP);      // 2048 stats + 256 tvec
    float* tvec  = stats + 2048;
    int*   segcnt= (int*)(tvec + 256);                   // nbkt*SEGSTR ints
    unsigned* bins = (unsigned*)(segcnt + (size_t)nbkt * SEGSTR);  // nbkt*SEGBIG u32

    int nb_binh = (E + CHUNK - 1) / CHUNK;
    dim3 ggrid((N + 127) / 128, 2);
    dim3 wgrid(8, 8);
    int  agrid = (N + 3) / 4;
    size_t n4 = (size_t)N * 64;

    // graph build + precasts
    k_zero <<<64, 256, 0, stream>>>(segcnt, nbkt, stats);
    k_zrow <<<1, 64, 0, stream>>>(B1, N);                 // sentinel row stays 0 all launch
    k_binh <<<nb_binh, 256, 0, stream>>>(row, col, bins, segcnt, E, nbkt);
    k_csr  <<<nbkt, 256, 0, stream>>>(bins, segcnt, csr, fillp, dinv, N);
    k_castx<<<2048, 256, 0, stream>>>(x, B0, n4);
    k_wt   <<<wgrid, 256, 0, stream>>>(W1, Wt,         nullptr);
    k_wt   <<<wgrid, 256, 0, stream>>>(W2, Wt + 65536, nullptr);

    // layer 1: hs1 = dinv*(xb@W1) -> B1 ; z1 -> B2
    k_gemm_bf16<<<ggrid, 256, 0, stream>>>(B0, Wt, B1, dinv, 1, nullptr, 0, N);
    k_agg_bf   <<<agrid, 256, 0, stream>>>(B1, B2, dinv, csr, fillp, b1, aptr, N);
    // layer 2: hs2 = dinv*(z1@W2) -> B1 ; z2 -> B0
    k_gemm_bf16<<<ggrid, 256, 0, stream>>>(B2, Wt + 65536, B1, dinv, 1, nullptr, 0, N);
    k_agg_bf   <<<agrid, 256, 0, stream>>>(B1, B0, dinv, csr, fillp, b2, aptr, N);
    // BN1 stats on z2; fold apply into proj weights
    k_bnstats_v<<<128, 256, 0, stream>>>(B0, stats, N);
    k_bnfinal  <<<1, 256, 0, stream>>>(stats, gamma, beta, 1.0f / (float)N);
    k_wt   <<<wgrid, 256, 0, stream>>>(projW, Wt + 131072, stats + 512);   // sc-scaled
    k_tvec <<<1, 256, 0, stream>>>(projW, stats + 768, tvec);              // t = sh@W
    // praw = z2b @ W' + t -> B1 ;  z (f32) = BN1(z2)
    k_gemm_bf16<<<ggrid, 256, 0, stream>>>(B0, Wt + 131072, B1, dinv, 0, tvec, 1, N);
    k_bnapply_z<<<2048, 256, 0, stream>>>(B0, zout, stats + 512, stats + 768, n4);
    // BN2 + prelu -> p
    k_bnstats_v<<<128, 256, 0, stream>>>(B1, stats + 1024, N);
    k_bnfinal  <<<1, 256, 0, stream>>>(stats + 1024, pgamma, pbeta, 1.0f / (float)N);
    k_bnapply_p<<<2048, 256, 0, stream>>>(B1, pout, stats + 1536, stats + 1792, a2ptr, n4);
}

// Round 11
// 692.146 us; speedup vs baseline: 1.0428x; 1.0428x over previous
//
#include <hip/hip_runtime.h>
#include <hip/hip_bf16.h>

// GCN (bf16): hs1 = dinv*(xb@W1); z1 = prelu(dv*(sum hs1)+b1); hs2 = dinv*(z1@W2);
// z2 = prelu(dv*(sum hs2)+b2); z = BN(z2) [f32]; p = prelu(BN2(z2 @ (sc*W) + sh@W))
// [BN1-apply folded into proj weights; proj_b cancels in BN2]; out = [z | p] (f32)
//
// R11: graph build back to R9 geometry (R10's CHUNK/NPB halving tripled
// reservation atomics -> +45us) but keeps line-padded segcnt; k_tvec parallel;
// agg: 2 nodes/wave, ushort8 (16B) lanes, 16-deep -> 2x rows in flight.

#define CAP 96          // max in-degree capacity (actual max deg ~60); multiple of 16
#define NPB 128         // nodes per bucket
#define CHUNK 4096      // edges per k_binh block
#define SEGBIG 4608     // entries per bucket segment (mean 4096 + 8 sigma)
#define MAXBKT 512      // supports N up to 65536
#define SEGSTR 16       // segcnt stride (ints) = one counter per 64B line

typedef __attribute__((ext_vector_type(8))) short short8;
typedef __attribute__((ext_vector_type(8))) unsigned short u16x8;
typedef __attribute__((ext_vector_type(4))) float f32x4;

__device__ __forceinline__ float bf2f(unsigned short u) {
    union { unsigned int i; float f; } v; v.i = ((unsigned int)u) << 16; return v.f;
}
__device__ __forceinline__ unsigned short f2bf(float f) {
    __hip_bfloat16 h = __float2bfloat16(f);   // RNE
    return *reinterpret_cast<unsigned short*>(&h);
}

// ---------------- zero: segcnt (line-strided), stats ----------------
__global__ __launch_bounds__(256) void k_zero(int* segcnt, int nbkt, float* stats) {
    int i = blockIdx.x * 256 + threadIdx.x;
    if (i < nbkt * SEGSTR) segcnt[i] = 0;
    if (i < 2048) stats[i] = 0.0f;
}

// zero sentinel row N of the gather-source buffer
__global__ __launch_bounds__(64) void k_zrow(unsigned short* hs, int N) {
    ((ushort4*)hs)[(size_t)N * 64 + threadIdx.x] = ushort4{0, 0, 0, 0};
}

// ---------------- phase 1: LDS-histogram binning by destination bucket ----------------
__global__ __launch_bounds__(256) void k_binh(const int* __restrict__ row, const int* __restrict__ col,
                                              unsigned* __restrict__ bins, int* __restrict__ segcnt,
                                              int E, int nbkt) {
    __shared__ int hist[MAXBKT];
    __shared__ int base[MAXBKT];
    int e0 = blockIdx.x * CHUNK;
    int eend = e0 + CHUNK; if (eend > E) eend = E;
    for (int b = threadIdx.x; b < nbkt; b += 256) hist[b] = 0;
    __syncthreads();
    for (int e = e0 + threadIdx.x; e < eend; e += 256)
        atomicAdd(&hist[col[e] >> 7], 1);
    __syncthreads();
    for (int b = threadIdx.x; b < nbkt; b += 256) {
        int h = hist[b];
        base[b] = h ? atomicAdd(&segcnt[b * SEGSTR], h) : 0;   // line-padded counter
        hist[b] = 0;                       // reuse as running offset
    }
    __syncthreads();
    for (int e = e0 + threadIdx.x; e < eend; e += 256) {
        int v = col[e], r = row[e];
        int b = v >> 7;
        int p = base[b] + atomicAdd(&hist[b], 1);
        if (p < SEGBIG) bins[(size_t)b * SEGBIG + p] = ((unsigned)r << 7) | (unsigned)(v & (NPB - 1));
    }
}

// ---------------- phase 2: per-bucket CSR scatter + dinv + pad-to-16 ----------------
__global__ __launch_bounds__(256) void k_csr(const unsigned* __restrict__ bins, const int* __restrict__ segcnt,
                                             int* __restrict__ csr, int* __restrict__ fillp,
                                             float* __restrict__ dinv, int N) {
    __shared__ int cnt[NPB];
    int bkt = blockIdx.x;
    if (threadIdx.x < NPB) cnt[threadIdx.x] = 0;
    __syncthreads();
    int m = segcnt[bkt * SEGSTR]; if (m > SEGBIG) m = SEGBIG;
    const unsigned* b = bins + (size_t)bkt * SEGBIG;
    for (int i = threadIdx.x; i < m; i += 256) {
        unsigned ent = b[i];
        int loc = (int)(ent & (NPB - 1));
        int r   = (int)(ent >> 7);
        int p = atomicAdd(&cnt[loc], 1);
        if (p < CAP) csr[(size_t)(bkt * NPB + loc) * CAP + p] = r;
    }
    __syncthreads();
    if (threadIdx.x < NPB) {
        int v = bkt * NPB + threadIdx.x;
        if (v < N) {
            int c = cnt[threadIdx.x];
            int real = c < CAP ? c : CAP;
            int pc = (real + 15) & ~15;           // pad to multiple of 16
            if (pc > CAP) pc = CAP;
            int* lst = csr + (size_t)v * CAP;
            for (int p = real; p < pc; ++p) lst[p] = N;   // sentinel: hs row N = 0
            fillp[v] = pc;
            dinv[v] = rsqrtf(1.0f + (float)c);    // +1 self loop
        }
    }
}

// ---------------- cast f32 -> bf16 (vectorized) ----------------
__global__ __launch_bounds__(256) void k_castx(const float* __restrict__ x, unsigned short* __restrict__ xb, size_t n4) {
    size_t stride = (size_t)gridDim.x * blockDim.x;
    for (size_t i = (size_t)blockIdx.x * blockDim.x + threadIdx.x; i < n4; i += stride) {
        float4 v = ((const float4*)x)[i];
        ushort4 o; o.x = f2bf(v.x); o.y = f2bf(v.y); o.z = f2bf(v.z); o.w = f2bf(v.w);
        ((ushort4*)xb)[i] = o;
    }
}

// ---------------- W [256,256] f32 -> Wt [n][k] bf16 (transpose+cast, opt. col-scale) --------
__global__ __launch_bounds__(256) void k_wt(const float* __restrict__ W, unsigned short* __restrict__ Wt,
                                            const float* __restrict__ scp) {
    __shared__ float t[32][33];
    int bx = blockIdx.x * 32, by = blockIdx.y * 32;
    int x = threadIdx.x & 31, y = threadIdx.x >> 5;   // 32x8
#pragma unroll
    for (int i = 0; i < 32; i += 8) {
        float s = scp ? scp[by + y + i] : 1.0f;
        t[y + i][x] = W[(size_t)(by + y + i) * 256 + bx + x] * s;
    }
    __syncthreads();
#pragma unroll
    for (int i = 0; i < 32; i += 8)
        Wt[(size_t)(bx + y + i) * 256 + by + x] = f2bf(t[x][y + i]);  // Wt[n][k] = sc[k]*W[k][n]
}

// ---------------- t[n] = sum_k sh[k]*W[k][n]  (parallel: 256 blocks x 64 lanes) ----------------
__global__ __launch_bounds__(64) void k_tvec(const float* __restrict__ W, const float* __restrict__ sh,
                                             float* __restrict__ tvec) {
    int n = blockIdx.x, l = threadIdx.x;
    float s = 0.0f;
    for (int k = l; k < 256; k += 64) s += sh[k] * W[(size_t)k * 256 + n];
#pragma unroll
    for (int off = 32; off; off >>= 1) s += __shfl_down(s, off);
    if (l == 0) tvec[n] = s;
}

// ---------------- bf16 MFMA GEMM + LDS-staged coalesced epilogue ----------------
// C[M,256] = A[M,256] @ B (Bt[n][k]); use_scale: *dinv[row]; use_bias: + tvec[col].
__global__ __launch_bounds__(256) void k_gemm_bf16(const unsigned short* __restrict__ A,
                                                   const unsigned short* __restrict__ Bt,
                                                   unsigned short* __restrict__ C,
                                                   const float* __restrict__ dinv, int use_scale,
                                                   const float* __restrict__ tvec, int use_bias,
                                                   int M) {
    __shared__ unsigned short buf[16384];     // As|Bs during K-loop; C-stage reuses all 32KB
    unsigned short* As = buf;
    unsigned short* Bs = buf + 8192;
    int tid  = threadIdx.x;
    int lane = tid & 63, wid = tid >> 6;
    int wr = wid >> 1, wc = wid & 1;
    int row0 = blockIdx.x * 128;
    int col0 = blockIdx.y * 128;

    f32x4 acc[4][4];
#pragma unroll
    for (int m = 0; m < 4; ++m)
#pragma unroll
        for (int n = 0; n < 4; ++n) acc[m][n] = f32x4{0.f, 0.f, 0.f, 0.f};

    int srow = lane >> 3;          // 0..7
    int sk   = (lane & 7) * 8;     // 0,8,...,56

    for (int k0 = 0; k0 < 256; k0 += 64) {
#pragma unroll
        for (int i = 0; i < 4; ++i) {
            int u = i * 4 + wid;                       // load unit 0..15, wave-uniform
            int arow = row0 + u * 8 + srow;
            if (arow >= M) arow = M - 1;               // per-lane source clamp (dest stays linear)
            const unsigned short* ga = A  + (size_t)arow * 256 + k0 + sk;
            const unsigned short* gb = Bt + (size_t)(col0 + u * 8 + srow) * 256 + k0 + sk;
            __builtin_amdgcn_global_load_lds((const __attribute__((address_space(1))) void*)ga,
                (__attribute__((address_space(3))) void*)(As + u * 512), 16, 0, 0);
            __builtin_amdgcn_global_load_lds((const __attribute__((address_space(1))) void*)gb,
                (__attribute__((address_space(3))) void*)(Bs + u * 512), 16, 0, 0);
        }
        __syncthreads();
#pragma unroll
        for (int kk = 0; kk < 64; kk += 32) {
            short8 a[4], b[4];
#pragma unroll
            for (int m = 0; m < 4; ++m)
                a[m] = *(const short8*)(As + (wr * 64 + m * 16 + (lane & 15)) * 64 + kk + (lane >> 4) * 8);
#pragma unroll
            for (int n = 0; n < 4; ++n)
                b[n] = *(const short8*)(Bs + (wc * 64 + n * 16 + (lane & 15)) * 64 + kk + (lane >> 4) * 8);
#pragma unroll
            for (int m = 0; m < 4; ++m)
#pragma unroll
                for (int n = 0; n < 4; ++n)
                    acc[m][n] = __builtin_amdgcn_mfma_f32_16x16x32_bf16(a[m], b[n], acc[m][n], 0, 0, 0);
        }
        __syncthreads();
    }

    // bias (f32, per-column) applied before bf16 staging
    float tn[4] = {0.f, 0.f, 0.f, 0.f};
    if (use_bias) {
#pragma unroll
        for (int n = 0; n < 4; ++n) tn[n] = tvec[col0 + wc * 64 + n * 16 + (lane & 15)];
    }
    // stage C tile (bf16) into LDS; MFMA C/D layout: col=lane&15, row=(lane>>4)*4+r
#pragma unroll
    for (int m = 0; m < 4; ++m)
#pragma unroll
        for (int r = 0; r < 4; ++r) {
            int lr = wr * 64 + m * 16 + (lane >> 4) * 4 + r;
#pragma unroll
            for (int n = 0; n < 4; ++n)
                buf[lr * 128 + wc * 64 + n * 16 + (lane & 15)] = f2bf(acc[m][n][r] + tn[n]);
        }
    __syncthreads();
    // coalesced store: 2048 chunks of 16B; optional per-row dinv prescale
#pragma unroll
    for (int j = 0; j < 8; ++j) {
        int c = j * 256 + tid;
        int r = c >> 4, cc = c & 15;
        int grow = row0 + r;
        if (grow < M) {
            short8 v = *(const short8*)(buf + r * 128 + cc * 8);
            if (use_scale) {
                float d = dinv[grow];
                short8 o;
#pragma unroll
                for (int t = 0; t < 8; ++t)
                    o[t] = (short)f2bf(bf2f((unsigned short)v[t]) * d);
                v = o;
            }
            *(short8*)(C + (size_t)grow * 256 + col0 + cc * 8) = v;
        }
    }
}

// ---------------- aggregation: 2 nodes/wave, 16B lanes, 16-deep ----------------
// half-wave (32 lanes x ushort8 = 256 ch) owns one node; out[v]=prelu(dv*sum+b)
__global__ __launch_bounds__(256) void k_agg_bf(const unsigned short* __restrict__ hs,
                                                unsigned short* __restrict__ outb,
                                                const float* __restrict__ dinv, const int* __restrict__ csr,
                                                const int* __restrict__ fillp, const float* __restrict__ bias,
                                                const float* __restrict__ aptr, int N) {
    int wv = threadIdx.x >> 6, lane = threadIdx.x & 63;
    int half = lane >> 5, hl = lane & 31;        // half-wave id, lane-in-half
    int v = blockIdx.x * 8 + wv * 2 + half;      // 8 nodes per block
    bool valid = v < N;
    int vread = valid ? v : N;                   // row N is the zero row
    const u16x8* h8 = (const u16x8*)hs;
    u16x8 hv = h8[(size_t)vread * 32 + hl];
    float s[8];
#pragma unroll
    for (int j = 0; j < 8; ++j) s[j] = bf2f((unsigned short)hv[j]);   // self term (prescaled)
    int n = valid ? fillp[v] : 0;                // multiple of 16
    const int* lst = csr + (size_t)(valid ? v : 0) * CAP;
    int nmax = max(n, __shfl_xor(n, 32));        // sync loop across the 2 halves
    for (int i = 0; i < nmax; i += 16) {
        int u[16];
#pragma unroll
        for (int t = 0; t < 16; ++t) u[t] = (i + t < n) ? lst[i + t] : N;
        u16x8 a[16];
#pragma unroll
        for (int t = 0; t < 16; ++t) a[t] = h8[(size_t)u[t] * 32 + hl];
#pragma unroll
        for (int t = 0; t < 16; ++t)
#pragma unroll
            for (int j = 0; j < 8; ++j) s[j] += bf2f((unsigned short)a[t][j]);
    }
    float dv = valid ? dinv[v] : 0.0f;
    float al = *aptr;
    float4 bb0 = *(const float4*)(bias + hl * 8);
    float4 bb1 = *(const float4*)(bias + hl * 8 + 4);
    float bbv[8] = {bb0.x, bb0.y, bb0.z, bb0.w, bb1.x, bb1.y, bb1.z, bb1.w};
    u16x8 o;
#pragma unroll
    for (int j = 0; j < 8; ++j) {
        float y = dv * s[j] + bbv[j];
        y = y >= 0.f ? y : al * y;
        o[j] = f2bf(y);
    }
    if (valid) ((u16x8*)outb)[(size_t)v * 32 + hl] = o;
}

// ---------------- BN column stats (vectorized ushort4) ----------------
__global__ __launch_bounds__(256) void k_bnstats_v(const unsigned short* __restrict__ X, float* __restrict__ sums, int N) {
    int w = threadIdx.x >> 6, lane = threadIdx.x & 63;
    int c4 = lane * 4;
    float4 s = {0.f, 0.f, 0.f, 0.f}, q = {0.f, 0.f, 0.f, 0.f};
    int rstride = gridDim.x * 4;
    for (int r = blockIdx.x * 4 + w; r < N; r += rstride) {
        ushort4 x4 = ((const ushort4*)X)[(size_t)r * 64 + lane];
        float a = bf2f(x4.x), b = bf2f(x4.y), c = bf2f(x4.z), d = bf2f(x4.w);
        s.x += a; s.y += b; s.z += c; s.w += d;
        q.x += a * a; q.y += b * b; q.z += c * c; q.w += d * d;
    }
    atomicAdd(&sums[c4 + 0], s.x); atomicAdd(&sums[c4 + 1], s.y);
    atomicAdd(&sums[c4 + 2], s.z); atomicAdd(&sums[c4 + 3], s.w);
    atomicAdd(&sums[256 + c4 + 0], q.x); atomicAdd(&sums[256 + c4 + 1], q.y);
    atomicAdd(&sums[256 + c4 + 2], q.z); atomicAdd(&sums[256 + c4 + 3], q.w);
}

__global__ __launch_bounds__(256) void k_bnfinal(float* stats, const float* __restrict__ gamma,
                                                 const float* __restrict__ beta, float invN) {
    int c = threadIdx.x;
    float mu = stats[c] * invN;
    float var = stats[256 + c] * invN - mu * mu;
    float rstd = rsqrtf(var + 1e-5f);
    float sc = rstd * gamma[c];
    stats[512 + c] = sc;
    stats[768 + c] = beta[c] - mu * sc;
}

// ---------------- BN apply for z: f32 out only ----------------
__global__ __launch_bounds__(256) void k_bnapply_z(const unsigned short* __restrict__ in,
                                                   float* __restrict__ zout,
                                                   const float* __restrict__ scale, const float* __restrict__ shift,
                                                   size_t n4) {
    size_t stride = (size_t)gridDim.x * blockDim.x;
    for (size_t i = (size_t)blockIdx.x * blockDim.x + threadIdx.x; i < n4; i += stride) {
        int c4 = (int)(i & 63) * 4;
        ushort4 x4 = ((const ushort4*)in)[i];
        float4 sc = *(const float4*)(scale + c4);
        float4 sh = *(const float4*)(shift + c4);
        float4 y;
        y.x = bf2f(x4.x) * sc.x + sh.x;
        y.y = bf2f(x4.y) * sc.y + sh.y;
        y.z = bf2f(x4.z) * sc.z + sh.z;
        y.w = bf2f(x4.w) * sc.w + sh.w;
        ((float4*)zout)[i] = y;
    }
}

// ---------------- BN apply for p: prelu, f32 out ----------------
__global__ __launch_bounds__(256) void k_bnapply_p(const unsigned short* __restrict__ in,
                                                   float* __restrict__ pout,
                                                   const float* __restrict__ scale, const float* __restrict__ shift,
                                                   const float* __restrict__ aptr, size_t n4) {
    size_t stride = (size_t)gridDim.x * blockDim.x;
    float a = *aptr;
    for (size_t i = (size_t)blockIdx.x * blockDim.x + threadIdx.x; i < n4; i += stride) {
        int c4 = (int)(i & 63) * 4;
        ushort4 x4 = ((const ushort4*)in)[i];
        float4 sc = *(const float4*)(scale + c4);
        float4 sh = *(const float4*)(shift + c4);
        float4 y;
        y.x = bf2f(x4.x) * sc.x + sh.x;
        y.y = bf2f(x4.y) * sc.y + sh.y;
        y.z = bf2f(x4.z) * sc.z + sh.z;
        y.w = bf2f(x4.w) * sc.w + sh.w;
        y.x = y.x >= 0.f ? y.x : a * y.x;
        y.y = y.y >= 0.f ? y.y : a * y.y;
        y.z = y.z >= 0.f ? y.z : a * y.z;
        y.w = y.w >= 0.f ? y.w : a * y.w;
        ((float4*)pout)[i] = y;
    }
}

extern "C" void kernel_launch(void* const* d_in, const int* in_sizes, int n_in,
                              void* d_out, int out_size, void* d_ws, size_t ws_size,
                              hipStream_t stream) {
    const float* x     = (const float*)d_in[0];
    const int*   ei    = (const int*)d_in[1];
    const float* W1    = (const float*)d_in[2];
    const float* b1    = (const float*)d_in[3];
    const float* W2    = (const float*)d_in[4];
    const float* b2    = (const float*)d_in[5];
    const float* aptr  = (const float*)d_in[6];
    const float* gamma = (const float*)d_in[7];
    const float* beta  = (const float*)d_in[8];
    const float* projW = (const float*)d_in[9];
    // d_in[10] = proj_b: cancels inside BN2, unused
    const float* pgamma = (const float*)d_in[11];
    const float* pbeta  = (const float*)d_in[12];
    const float* a2ptr  = (const float*)d_in[13];

    int N = in_sizes[0] / 256;
    int E = in_sizes[1] / 2;
    const int* row = ei;
    const int* col = ei + E;

    float* out  = (float*)d_out;
    float* zout = out;
    float* pout = out + (size_t)N * 256;

    int nbkt = (N + NPB - 1) / NPB;

    // workspace: B0|B1|B2 bf16 [(N+1),256], Wt x3, dinv, fillp, csr, stats(+tvec), segcnt, bins
    size_t rowsz = (size_t)(N + 1) * 256;
    unsigned short* B0 = (unsigned short*)d_ws;
    unsigned short* B1 = B0 + rowsz;
    unsigned short* B2 = B1 + rowsz;
    unsigned short* Wt = B2 + rowsz;
    float* dinv  = (float*)(Wt + 3 * 65536);
    int*   fillp = (int*)(dinv + N + 1);
    int*   csr   = fillp + N;
    float* stats = (float*)(csr + (size_t)N * CAP);      // 2048 stats + 256 tvec
    float* tvec  = stats + 2048;
    int*   segcnt= (int*)(tvec + 256);                   // nbkt*SEGSTR ints
    unsigned* bins = (unsigned*)(segcnt + (size_t)nbkt * SEGSTR);  // nbkt*SEGBIG u32

    int nb_binh = (E + CHUNK - 1) / CHUNK;
    dim3 ggrid((N + 127) / 128, 2);
    dim3 wgrid(8, 8);
    int  agrid = (N + 7) / 8;
    size_t n4 = (size_t)N * 64;

    // graph build + precasts
    k_zero <<<32, 256, 0, stream>>>(segcnt, nbkt, stats);
    k_zrow <<<1, 64, 0, stream>>>(B1, N);                 // sentinel row stays 0 all launch
    k_binh <<<nb_binh, 256, 0, stream>>>(row, col, bins, segcnt, E, nbkt);
    k_csr  <<<nbkt, 256, 0, stream>>>(bins, segcnt, csr, fillp, dinv, N);
    k_castx<<<2048, 256, 0, stream>>>(x, B0, n4);
    k_wt   <<<wgrid, 256, 0, stream>>>(W1, Wt,         nullptr);
    k_wt   <<<wgrid, 256, 0, stream>>>(W2, Wt + 65536, nullptr);

    // layer 1: hs1 = dinv*(xb@W1) -> B1 ; z1 -> B2
    k_gemm_bf16<<<ggrid, 256, 0, stream>>>(B0, Wt, B1, dinv, 1, nullptr, 0, N);
    k_agg_bf   <<<agrid, 256, 0, stream>>>(B1, B2, dinv, csr, fillp, b1, aptr, N);
    // layer 2: hs2 = dinv*(z1@W2) -> B1 ; z2 -> B0
    k_gemm_bf16<<<ggrid, 256, 0, stream>>>(B2, Wt + 65536, B1, dinv, 1, nullptr, 0, N);
    k_agg_bf   <<<agrid, 256, 0, stream>>>(B1, B0, dinv, csr, fillp, b2, aptr, N);
    // BN1 stats on z2; fold apply into proj weights
    k_bnstats_v<<<128, 256, 0, stream>>>(B0, stats, N);
    k_bnfinal  <<<1, 256, 0, stream>>>(stats, gamma, beta, 1.0f / (float)N);
    k_wt   <<<wgrid, 256, 0, stream>>>(projW, Wt + 131072, stats + 512);   // sc-scaled
    k_tvec <<<256, 64, 0, stream>>>(projW, stats + 768, tvec);             // t = sh@W
    // praw = z2b @ W' + t -> B1 ;  z (f32) = BN1(z2)
    k_gemm_bf16<<<ggrid, 256, 0, stream>>>(B0, Wt + 131072, B1, dinv, 0, tvec, 1, N);
    k_bnapply_z<<<2048, 256, 0, stream>>>(B0, zout, stats + 512, stats + 768, n4);
    // BN2 + prelu -> p
    k_bnstats_v<<<128, 256, 0, stream>>>(B1, stats + 1024, N);
    k_bnfinal  <<<1, 256, 0, stream>>>(stats + 1024, pgamma, pbeta, 1.0f / (float)N);
    k_bnapply_p<<<2048, 256, 0, stream>>>(B1, pout, stats + 1536, stats + 1792, a2ptr, n4);
}

// Round 12
// 681.736 us; speedup vs baseline: 1.0587x; 1.0153x over previous
//
#include <hip/hip_runtime.h>
#include <hip/hip_bf16.h>

// GCN (bf16): hs1 = dinv*(xb@W1); z1 = prelu(dv*(sum hs1)+b1); hs2 = dinv*(z1@W2);
// z2 = prelu(dv*(sum hs2)+b2); z = BN1(z2) [written inside proj GEMM];
// p = prelu(BN2(z2 @ (sc1*W) + sh1@W)) [BN1 folded into proj weights; proj_b cancels]
// out = [z | p] (f32)
//
// R12: 20 -> 12 kernels. k_setup fuses zero/zrow/castx/wt1/wt2; bnfinal deleted
// (consumers recompute scale/shift from raw sums); bnapply_z fused into gemm3
// epilogue (z2 tiles already staged in LDS). Agg reverted to R9 (its BW floor:
// 105us, ~8TB/s effective gather through cache hierarchy; R10/R11 variants null).

#define CAP 96          // max in-degree capacity (actual max deg ~60); multiple of 16
#define NPB 128         // nodes per bucket
#define CHUNK 4096      // edges per k_binh block
#define SEGBIG 4608     // entries per bucket segment (mean 4096 + 8 sigma)
#define MAXBKT 512      // supports N up to 65536
#define SEGSTR 16       // segcnt stride (ints) = one counter per 64B line
#define BNEPS 1e-5f

typedef __attribute__((ext_vector_type(8))) short short8;
typedef __attribute__((ext_vector_type(4))) float f32x4;

__device__ __forceinline__ float bf2f(unsigned short u) {
    union { unsigned int i; float f; } v; v.i = ((unsigned int)u) << 16; return v.f;
}
__device__ __forceinline__ unsigned short f2bf(float f) {
    __hip_bfloat16 h = __float2bfloat16(f);   // RNE
    return *reinterpret_cast<unsigned short*>(&h);
}

// ---------------- fused setup: castx | wt1 | wt2 | zero | zrow ----------------
// blocks [0,1024): castx; [1024,1088): wt1; [1088,1152): wt2; [1152,1184): zero; 1184: zrow
__global__ __launch_bounds__(256) void k_setup(const float* __restrict__ x, unsigned short* __restrict__ xb,
                                               const float* __restrict__ W1, unsigned short* __restrict__ Wt1,
                                               const float* __restrict__ W2, unsigned short* __restrict__ Wt2,
                                               int* segcnt, int nbkt, float* stats,
                                               unsigned short* zrowbuf, int N, size_t n4) {
    int bid = blockIdx.x;
    if (bid < 1024) {                       // castx (grid-stride)
        size_t stride = (size_t)1024 * 256;
        for (size_t i = (size_t)bid * 256 + threadIdx.x; i < n4; i += stride) {
            float4 v = ((const float4*)x)[i];
            ushort4 o; o.x = f2bf(v.x); o.y = f2bf(v.y); o.z = f2bf(v.z); o.w = f2bf(v.w);
            ((ushort4*)xb)[i] = o;
        }
    } else if (bid < 1152) {                // wt1 / wt2 transpose+cast
        const float* W = bid < 1088 ? W1 : W2;
        unsigned short* Wt = bid < 1088 ? Wt1 : Wt2;
        int widx = (bid - 1024) & 63;
        int bx = (widx & 7) * 32, by = (widx >> 3) * 32;
        __shared__ float t[32][33];
        int xx = threadIdx.x & 31, yy = threadIdx.x >> 5;
#pragma unroll
        for (int i = 0; i < 32; i += 8)
            t[yy + i][xx] = W[(size_t)(by + yy + i) * 256 + bx + xx];
        __syncthreads();
#pragma unroll
        for (int i = 0; i < 32; i += 8)
            Wt[(size_t)(bx + yy + i) * 256 + by + xx] = f2bf(t[xx][yy + i]);
    } else if (bid < 1184) {                // zero segcnt + stats
        int i = (bid - 1152) * 256 + threadIdx.x;
        if (i < nbkt * SEGSTR) segcnt[i] = 0;
        if (i < 2048) stats[i] = 0.0f;
    } else {                                // zero sentinel row N of hs buffer
        if (threadIdx.x < 64)
            ((ushort4*)zrowbuf)[(size_t)N * 64 + threadIdx.x] = ushort4{0, 0, 0, 0};
    }
}

// ---------------- phase 1: LDS-histogram binning by destination bucket ----------------
__global__ __launch_bounds__(256) void k_binh(const int* __restrict__ row, const int* __restrict__ col,
                                              unsigned* __restrict__ bins, int* __restrict__ segcnt,
                                              int E, int nbkt) {
    __shared__ int hist[MAXBKT];
    __shared__ int base[MAXBKT];
    int e0 = blockIdx.x * CHUNK;
    int eend = e0 + CHUNK; if (eend > E) eend = E;
    for (int b = threadIdx.x; b < nbkt; b += 256) hist[b] = 0;
    __syncthreads();
    for (int e = e0 + threadIdx.x; e < eend; e += 256)
        atomicAdd(&hist[col[e] >> 7], 1);
    __syncthreads();
    for (int b = threadIdx.x; b < nbkt; b += 256) {
        int h = hist[b];
        base[b] = h ? atomicAdd(&segcnt[b * SEGSTR], h) : 0;   // line-padded counter
        hist[b] = 0;                       // reuse as running offset
    }
    __syncthreads();
    for (int e = e0 + threadIdx.x; e < eend; e += 256) {
        int v = col[e], r = row[e];
        int b = v >> 7;
        int p = base[b] + atomicAdd(&hist[b], 1);
        if (p < SEGBIG) bins[(size_t)b * SEGBIG + p] = ((unsigned)r << 7) | (unsigned)(v & (NPB - 1));
    }
}

// ---------------- phase 2: per-bucket CSR scatter + dinv + pad-to-16 ----------------
__global__ __launch_bounds__(256) void k_csr(const unsigned* __restrict__ bins, const int* __restrict__ segcnt,
                                             int* __restrict__ csr, int* __restrict__ fillp,
                                             float* __restrict__ dinv, int N) {
    __shared__ int cnt[NPB];
    int bkt = blockIdx.x;
    if (threadIdx.x < NPB) cnt[threadIdx.x] = 0;
    __syncthreads();
    int m = segcnt[bkt * SEGSTR]; if (m > SEGBIG) m = SEGBIG;
    const unsigned* b = bins + (size_t)bkt * SEGBIG;
    for (int i = threadIdx.x; i < m; i += 256) {
        unsigned ent = b[i];
        int loc = (int)(ent & (NPB - 1));
        int r   = (int)(ent >> 7);
        int p = atomicAdd(&cnt[loc], 1);
        if (p < CAP) csr[(size_t)(bkt * NPB + loc) * CAP + p] = r;
    }
    __syncthreads();
    if (threadIdx.x < NPB) {
        int v = bkt * NPB + threadIdx.x;
        if (v < N) {
            int c = cnt[threadIdx.x];
            int real = c < CAP ? c : CAP;
            int pc = (real + 15) & ~15;           // pad to multiple of 16
            if (pc > CAP) pc = CAP;
            int* lst = csr + (size_t)v * CAP;
            for (int p = real; p < pc; ++p) lst[p] = N;   // sentinel: hs row N = 0
            fillp[v] = pc;
            dinv[v] = rsqrtf(1.0f + (float)c);    // +1 self loop
        }
    }
}

// ---------------- wt3 (BN1-scaled proj transpose) + tvec, bnfinal recomputed locally ----
// blocks [0,64): Wt3[n][k] = sc1[k]*projW[k][n]; block 64: tvec[n] = sum_k sh1[k]*W[k][n]
__global__ __launch_bounds__(256) void k_wtb(const float* __restrict__ W, unsigned short* __restrict__ Wt,
                                             const float* __restrict__ sums,   // BN1 raw sums (stats)
                                             const float* __restrict__ gamma, const float* __restrict__ beta,
                                             float invN, float* __restrict__ tvec) {
    int bid = blockIdx.x;
    if (bid < 64) {
        int bx = (bid & 7) * 32, by = (bid >> 3) * 32;
        __shared__ float t[32][33];
        int xx = threadIdx.x & 31, yy = threadIdx.x >> 5;
#pragma unroll
        for (int i = 0; i < 32; i += 8) {
            int k = by + yy + i;
            float mu = sums[k] * invN;
            float var = sums[256 + k] * invN - mu * mu;
            float sc = rsqrtf(var + BNEPS) * gamma[k];
            t[yy + i][xx] = W[(size_t)k * 256 + bx + xx] * sc;
        }
        __syncthreads();
#pragma unroll
        for (int i = 0; i < 32; i += 8)
            Wt[(size_t)(bx + yy + i) * 256 + by + xx] = f2bf(t[xx][yy + i]);
    } else {
        int n = threadIdx.x;
        float s = 0.0f;
        for (int k = 0; k < 256; ++k) {
            float mu = sums[k] * invN;
            float var = sums[256 + k] * invN - mu * mu;
            float sc = rsqrtf(var + BNEPS) * gamma[k];
            float sh = beta[k] - mu * sc;
            s += sh * W[(size_t)k * 256 + n];
        }
        tvec[n] = s;
    }
}

// ---------------- bf16 MFMA GEMM + LDS-staged coalesced epilogue ----------------
// C[M,256] = A[M,256] @ B (Bt[n][k]); use_scale: *dinv[row]; use_bias: + tvec[col];
// writez: blockIdx.y==0 blocks also write zout = BN1(A) (BN recomputed from raw sums).
__global__ __launch_bounds__(256) void k_gemm_bf16(const unsigned short* __restrict__ A,
                                                   const unsigned short* __restrict__ Bt,
                                                   unsigned short* __restrict__ C,
                                                   const float* __restrict__ dinv, int use_scale,
                                                   const float* __restrict__ tvec, int use_bias,
                                                   const float* __restrict__ bnsums,
                                                   const float* __restrict__ gamma, const float* __restrict__ beta,
                                                   float invN, float* __restrict__ zout, int writez,
                                                   int M) {
    __shared__ unsigned short buf[16384];     // As|Bs during K-loop; C-stage reuses all 32KB
    __shared__ float zsc[256], zsh[256];
    unsigned short* As = buf;
    unsigned short* Bs = buf + 8192;
    int tid  = threadIdx.x;
    int lane = tid & 63, wid = tid >> 6;
    int wr = wid >> 1, wc = wid & 1;
    int row0 = blockIdx.x * 128;
    int col0 = blockIdx.y * 128;

    if (writez) {
        int c = tid;
        float mu = bnsums[c] * invN;
        float var = bnsums[256 + c] * invN - mu * mu;
        float sc = rsqrtf(var + BNEPS) * gamma[c];
        zsc[c] = sc; zsh[c] = beta[c] - mu * sc;
    }

    f32x4 acc[4][4];
#pragma unroll
    for (int m = 0; m < 4; ++m)
#pragma unroll
        for (int n = 0; n < 4; ++n) acc[m][n] = f32x4{0.f, 0.f, 0.f, 0.f};

    int srow = lane >> 3;          // 0..7
    int sk   = (lane & 7) * 8;     // 0,8,...,56

    for (int k0 = 0; k0 < 256; k0 += 64) {
#pragma unroll
        for (int i = 0; i < 4; ++i) {
            int u = i * 4 + wid;                       // load unit 0..15, wave-uniform
            int arow = row0 + u * 8 + srow;
            if (arow >= M) arow = M - 1;               // per-lane source clamp (dest stays linear)
            const unsigned short* ga = A  + (size_t)arow * 256 + k0 + sk;
            const unsigned short* gb = Bt + (size_t)(col0 + u * 8 + srow) * 256 + k0 + sk;
            __builtin_amdgcn_global_load_lds((const __attribute__((address_space(1))) void*)ga,
                (__attribute__((address_space(3))) void*)(As + u * 512), 16, 0, 0);
            __builtin_amdgcn_global_load_lds((const __attribute__((address_space(1))) void*)gb,
                (__attribute__((address_space(3))) void*)(Bs + u * 512), 16, 0, 0);
        }
        __syncthreads();
        // fused z-write: As holds A[row0+r][k0+kk] as As[(r>>3)*512+(r&7)*64+kk]
        if (writez && blockIdx.y == 0) {
#pragma unroll
            for (int j = 0; j < 4; ++j) {
                int r = j * 32 + (tid >> 3);
                int kk = (tid & 7) * 8;
                int grow = row0 + r;
                if (grow < M) {
                    short8 v = *(const short8*)(As + (r >> 3) * 512 + (r & 7) * 64 + kk);
                    float* zp = zout + (size_t)grow * 256 + k0 + kk;
#pragma unroll
                    for (int t = 0; t < 8; ++t)
                        zp[t] = bf2f((unsigned short)v[t]) * zsc[k0 + kk + t] + zsh[k0 + kk + t];
                }
            }
        }
#pragma unroll
        for (int kk = 0; kk < 64; kk += 32) {
            short8 a[4], b[4];
#pragma unroll
            for (int m = 0; m < 4; ++m)
                a[m] = *(const short8*)(As + (wr * 64 + m * 16 + (lane & 15)) * 64 + kk + (lane >> 4) * 8);
#pragma unroll
            for (int n = 0; n < 4; ++n)
                b[n] = *(const short8*)(Bs + (wc * 64 + n * 16 + (lane & 15)) * 64 + kk + (lane >> 4) * 8);
#pragma unroll
            for (int m = 0; m < 4; ++m)
#pragma unroll
                for (int n = 0; n < 4; ++n)
                    acc[m][n] = __builtin_amdgcn_mfma_f32_16x16x32_bf16(a[m], b[n], acc[m][n], 0, 0, 0);
        }
        __syncthreads();
    }

    // bias (f32, per-column) applied before bf16 staging
    float tn[4] = {0.f, 0.f, 0.f, 0.f};
    if (use_bias) {
#pragma unroll
        for (int n = 0; n < 4; ++n) tn[n] = tvec[col0 + wc * 64 + n * 16 + (lane & 15)];
    }
    // stage C tile (bf16) into LDS; MFMA C/D layout: col=lane&15, row=(lane>>4)*4+r
#pragma unroll
    for (int m = 0; m < 4; ++m)
#pragma unroll
        for (int r = 0; r < 4; ++r) {
            int lr = wr * 64 + m * 16 + (lane >> 4) * 4 + r;
#pragma unroll
            for (int n = 0; n < 4; ++n)
                buf[lr * 128 + wc * 64 + n * 16 + (lane & 15)] = f2bf(acc[m][n][r] + tn[n]);
        }
    __syncthreads();
    // coalesced store: 2048 chunks of 16B; optional per-row dinv prescale
#pragma unroll
    for (int j = 0; j < 8; ++j) {
        int c = j * 256 + tid;
        int r = c >> 4, cc = c & 15;
        int grow = row0 + r;
        if (grow < M) {
            short8 v = *(const short8*)(buf + r * 128 + cc * 8);
            if (use_scale) {
                float d = dinv[grow];
                short8 o;
#pragma unroll
                for (int t = 0; t < 8; ++t)
                    o[t] = (short)f2bf(bf2f((unsigned short)v[t]) * d);
                v = o;
            }
            *(short8*)(C + (size_t)grow * 256 + col0 + cc * 8) = v;
        }
    }
}

// ---------------- aggregation: pure 16-wide row sum (R9 version — BW floor) ----------------
__global__ __launch_bounds__(256) void k_agg_bf(const unsigned short* __restrict__ hs,
                                                unsigned short* __restrict__ outb,
                                                const float* __restrict__ dinv, const int* __restrict__ csr,
                                                const int* __restrict__ fillp, const float* __restrict__ bias,
                                                const float* __restrict__ aptr, int N) {
    int wv = threadIdx.x >> 6, lane = threadIdx.x & 63;   // one node per wave, 4 ch/lane
    int v = blockIdx.x * 4 + wv;
    if (v >= N) return;
    const ushort4* h4 = (const ushort4*)hs;
    float dv = dinv[v];
    ushort4 hv = h4[(size_t)v * 64 + lane];
    float s0 = bf2f(hv.x), s1 = bf2f(hv.y), s2 = bf2f(hv.z), s3 = bf2f(hv.w);
    int n = fillp[v];                      // multiple of 16 (sentinel-padded)
    const int* lst = csr + (size_t)v * CAP;
    for (int i = 0; i < n; i += 16) {
        int u[16];
        ushort4 a[16];
#pragma unroll
        for (int t = 0; t < 16; ++t) u[t] = lst[i + t];
#pragma unroll
        for (int t = 0; t < 16; ++t) a[t] = h4[(size_t)u[t] * 64 + lane];
#pragma unroll
        for (int t = 0; t < 16; ++t) {
            s0 += bf2f(a[t].x); s1 += bf2f(a[t].y);
            s2 += bf2f(a[t].z); s3 += bf2f(a[t].w);
        }
    }
    float al = *aptr;
    float4 bb = *(const float4*)(bias + lane * 4);
    float o0 = dv * s0 + bb.x, o1 = dv * s1 + bb.y, o2 = dv * s2 + bb.z, o3 = dv * s3 + bb.w;
    o0 = o0 >= 0.f ? o0 : al * o0;
    o1 = o1 >= 0.f ? o1 : al * o1;
    o2 = o2 >= 0.f ? o2 : al * o2;
    o3 = o3 >= 0.f ? o3 : al * o3;
    ushort4 o; o.x = f2bf(o0); o.y = f2bf(o1); o.z = f2bf(o2); o.w = f2bf(o3);
    ((ushort4*)outb)[(size_t)v * 64 + lane] = o;
}

// ---------------- BN column stats (vectorized ushort4) ----------------
__global__ __launch_bounds__(256) void k_bnstats_v(const unsigned short* __restrict__ X, float* __restrict__ sums, int N) {
    int w = threadIdx.x >> 6, lane = threadIdx.x & 63;
    int c4 = lane * 4;
    float4 s = {0.f, 0.f, 0.f, 0.f}, q = {0.f, 0.f, 0.f, 0.f};
    int rstride = gridDim.x * 4;
    for (int r = blockIdx.x * 4 + w; r < N; r += rstride) {
        ushort4 x4 = ((const ushort4*)X)[(size_t)r * 64 + lane];
        float a = bf2f(x4.x), b = bf2f(x4.y), c = bf2f(x4.z), d = bf2f(x4.w);
        s.x += a; s.y += b; s.z += c; s.w += d;
        q.x += a * a; q.y += b * b; q.z += c * c; q.w += d * d;
    }
    atomicAdd(&sums[c4 + 0], s.x); atomicAdd(&sums[c4 + 1], s.y);
    atomicAdd(&sums[c4 + 2], s.z); atomicAdd(&sums[c4 + 3], s.w);
    atomicAdd(&sums[256 + c4 + 0], q.x); atomicAdd(&sums[256 + c4 + 1], q.y);
    atomicAdd(&sums[256 + c4 + 2], q.z); atomicAdd(&sums[256 + c4 + 3], q.w);
}

// ---------------- BN2-apply + prelu (bnfinal recomputed locally) ----------------
__global__ __launch_bounds__(256) void k_bnp(const unsigned short* __restrict__ in,
                                             float* __restrict__ pout,
                                             const float* __restrict__ sums,   // BN2 raw sums
                                             const float* __restrict__ gamma, const float* __restrict__ beta,
                                             float invN, const float* __restrict__ aptr, size_t n4) {
    __shared__ float psc[256], psh[256];
    {
        int c = threadIdx.x;
        float mu = sums[c] * invN;
        float var = sums[256 + c] * invN - mu * mu;
        float sc = rsqrtf(var + BNEPS) * gamma[c];
        psc[c] = sc; psh[c] = beta[c] - mu * sc;
    }
    __syncthreads();
    size_t stride = (size_t)gridDim.x * blockDim.x;
    float a = *aptr;
    for (size_t i = (size_t)blockIdx.x * blockDim.x + threadIdx.x; i < n4; i += stride) {
        int c4 = (int)(i & 63) * 4;
        ushort4 x4 = ((const ushort4*)in)[i];
        float4 y;
        y.x = bf2f(x4.x) * psc[c4 + 0] + psh[c4 + 0];
        y.y = bf2f(x4.y) * psc[c4 + 1] + psh[c4 + 1];
        y.z = bf2f(x4.z) * psc[c4 + 2] + psh[c4 + 2];
        y.w = bf2f(x4.w) * psc[c4 + 3] + psh[c4 + 3];
        y.x = y.x >= 0.f ? y.x : a * y.x;
        y.y = y.y >= 0.f ? y.y : a * y.y;
        y.z = y.z >= 0.f ? y.z : a * y.z;
        y.w = y.w >= 0.f ? y.w : a * y.w;
        ((float4*)pout)[i] = y;
    }
}

extern "C" void kernel_launch(void* const* d_in, const int* in_sizes, int n_in,
                              void* d_out, int out_size, void* d_ws, size_t ws_size,
                              hipStream_t stream) {
    const float* x     = (const float*)d_in[0];
    const int*   ei    = (const int*)d_in[1];
    const float* W1    = (const float*)d_in[2];
    const float* b1    = (const float*)d_in[3];
    const float* W2    = (const float*)d_in[4];
    const float* b2    = (const float*)d_in[5];
    const float* aptr  = (const float*)d_in[6];
    const float* gamma = (const float*)d_in[7];
    const float* beta  = (const float*)d_in[8];
    const float* projW = (const float*)d_in[9];
    // d_in[10] = proj_b: cancels inside BN2, unused
    const float* pgamma = (const float*)d_in[11];
    const float* pbeta  = (const float*)d_in[12];
    const float* a2ptr  = (const float*)d_in[13];

    int N = in_sizes[0] / 256;
    int E = in_sizes[1] / 2;
    const int* row = ei;
    const int* col = ei + E;

    float* out  = (float*)d_out;
    float* zout = out;
    float* pout = out + (size_t)N * 256;

    int nbkt = (N + NPB - 1) / NPB;
    float invN = 1.0f / (float)N;

    // workspace: B0|B1|B2 bf16 [(N+1),256], Wt x3, dinv, fillp, csr, stats(+tvec), segcnt, bins
    size_t rowsz = (size_t)(N + 1) * 256;
    unsigned short* B0 = (unsigned short*)d_ws;
    unsigned short* B1 = B0 + rowsz;
    unsigned short* B2 = B1 + rowsz;
    unsigned short* Wt = B2 + rowsz;
    float* dinv  = (float*)(Wt + 3 * 65536);
    int*   fillp = (int*)(dinv + N + 1);
    int*   csr   = fillp + N;
    float* stats = (float*)(csr + (size_t)N * CAP);      // 2048 stats + 256 tvec
    float* tvec  = stats + 2048;
    int*   segcnt= (int*)(tvec + 256);                   // nbkt*SEGSTR ints
    unsigned* bins = (unsigned*)(segcnt + (size_t)nbkt * SEGSTR);  // nbkt*SEGBIG u32

    int nb_binh = (E + CHUNK - 1) / CHUNK;
    dim3 ggrid((N + 127) / 128, 2);
    int  agrid = (N + 3) / 4;
    size_t n4 = (size_t)N * 64;

    // 1. fused setup (castx | wt1 | wt2 | zero | zrow on B1)
    k_setup<<<1185, 256, 0, stream>>>(x, B0, W1, Wt, W2, Wt + 65536,
                                      segcnt, nbkt, stats, B1, N, n4);
    // 2-3. graph build
    k_binh <<<nb_binh, 256, 0, stream>>>(row, col, bins, segcnt, E, nbkt);
    k_csr  <<<nbkt, 256, 0, stream>>>(bins, segcnt, csr, fillp, dinv, N);
    // 4-5. layer 1: hs1 = dinv*(xb@W1) -> B1 ; z1 -> B2
    k_gemm_bf16<<<ggrid, 256, 0, stream>>>(B0, Wt, B1, dinv, 1, nullptr, 0,
                                           nullptr, nullptr, nullptr, 0.f, nullptr, 0, N);
    k_agg_bf   <<<agrid, 256, 0, stream>>>(B1, B2, dinv, csr, fillp, b1, aptr, N);
    // 6-7. layer 2: hs2 = dinv*(z1@W2) -> B1 ; z2 -> B0
    k_gemm_bf16<<<ggrid, 256, 0, stream>>>(B2, Wt + 65536, B1, dinv, 1, nullptr, 0,
                                           nullptr, nullptr, nullptr, 0.f, nullptr, 0, N);
    k_agg_bf   <<<agrid, 256, 0, stream>>>(B1, B0, dinv, csr, fillp, b2, aptr, N);
    // 8. BN1 raw sums on z2
    k_bnstats_v<<<128, 256, 0, stream>>>(B0, stats, N);
    // 9. proj weights with BN1 scale folded + tvec (bnfinal recomputed locally)
    k_wtb<<<65, 256, 0, stream>>>(projW, Wt + 131072, stats, gamma, beta, invN, tvec);
    // 10. praw = z2b @ W' + t -> B1 ; fused z = BN1(z2) write (y==0 blocks)
    k_gemm_bf16<<<ggrid, 256, 0, stream>>>(B0, Wt + 131072, B1, dinv, 0, tvec, 1,
                                           stats, gamma, beta, invN, zout, 1, N);
    // 11. BN2 raw sums on praw
    k_bnstats_v<<<128, 256, 0, stream>>>(B1, stats + 1024, N);
    // 12. p = prelu(BN2(praw))
    k_bnp<<<2048, 256, 0, stream>>>(B1, pout, stats + 1024, pgamma, pbeta, invN, a2ptr, n4);
}